// Round 2
// baseline (114476.941 us; speedup 1.0000x reference)
//
#include <hip/hip_runtime.h>
#include <hip/hip_cooperative_groups.h>
#include <math.h>

namespace cg = cooperative_groups;

// Problem constants (fixed by setup_inputs)
#define TT  256   // scan steps
#define BB  32    // batch
#define EE  1024  // embed dim
#define MM  4096  // mlp dim
#define VV  4096  // vocab
#define BE  (BB*EE)      // 32768
#define NROWS (TT*BB)    // 8192
#define EPSF 1.1920929e-07f

// ======================= cooperative persistent scan =======================
// Per step, 6 grid-synced stages:
//  A: z1part[s][b][m] = sum_{e in slice s} inp*bnw0*fc1w0   (+seed hbuf=inp+fc2b0, ssA=sum inp^2)
//  B: hbuf += silu(rinvA*sum_s z1part + fc1b0) @ fc2w0^T    (seeded atomics)
//  C: z2part from hbuf*bnw1*fc1w1                           (+seed s=hbuf+inp+fc2b1, ssH)
//  D: s += silu(rinvH*sum_s z2part + fc1b1) @ fc2w1^T
//  E: npart[s][b][m] = sum_{e in slice} s*nw*nxtw           (ssS)
//  F: nxt = rinvS*sum_s npart + nxtb; inp_{t+1} = emb[tok]+nxt

struct ScanParams {
  const int* tokens;
  const float* embw;
  const float* bnw;
  const float* fc1w;
  const float* fc1b;
  const float* fc2w;
  const float* fc2b;
  const float* nw;
  const float* nxtw;
  const float* nxtb;
  float* inp_all;   // [TT][32][EE] (in d_out)
  float* s_all;     // [TT][32][EE] (in d_out)
  float* nxt_all;   // [TT][32][EE] (ws)
  float* zpart;     // 1,048,576 floats (ws)
  float* hbuf;      // [32][EE]
  float* ssA;       // [TT][32]
  float* ssH;       // [TT][32]
  float* ssS;       // [TT][32]
  float* zeroBase;  // ssA.. (3*TT*32 + 2*NROWS + 1 floats to clear)
};

// Generic fc1-style partial GEMM: zpart[ks][b][m] = sum_{e in slice}
// a[b][e]*scl[e]*W[m][e].  Tile 32 rows x 64 cols, 4x2 per thread.
// cg==0 blocks also: accumulate ssOut[b] += sum a^2 (their e-slice), and
// optionally write seedDst = a + seedBias (+ seedAdd).
__device__ inline void stage_fc1(int blk,
    const float* __restrict__ a, const float* __restrict__ scl,
    const float* __restrict__ W, int mtot, int ncg, int nks,
    float* __restrict__ zpart, float* __restrict__ ssOut,
    float* __restrict__ seedDst, const float* __restrict__ seedAdd,
    const float* __restrict__ seedBias,
    float* __restrict__ As, float* __restrict__ Ws) {
  if (blk >= ncg * nks) return;
  const int tid = threadIdx.x;
  const int cgi = blk % ncg, ks = blk / ncg;
  const int eslice = EE / nks;
  const int e0base = ks * eslice;
  const int tx = tid & 31, ty = tid >> 5;
  const int m0 = cgi * 64;
  float acc[4][2] = {{0.f,0.f},{0.f,0.f},{0.f,0.f},{0.f,0.f}};
  float ssacc[4] = {0.f,0.f,0.f,0.f};
  const bool lead = (cgi == 0);
  for (int c0 = 0; c0 < eslice; c0 += 32) {
    const int e0 = e0base + c0;
    {
      int idx = tid;
#pragma unroll
      for (int j = 0; j < 4; ++j, idx += 256) {
        int k = idx & 31, b = idx >> 5;
        float v = a[b * EE + e0 + k];
        ssacc[j] += v * v;
        As[k * 36 + b] = v * scl[e0 + k];
        if (lead && seedDst) {
          float d = v + seedBias[e0 + k];
          if (seedAdd) d += seedAdd[b * EE + e0 + k];
          seedDst[b * EE + e0 + k] = d;
        }
      }
    }
    {
      int idx = tid;
#pragma unroll
      for (int j = 0; j < 8; ++j, idx += 256) {
        int k = idx & 31, m = idx >> 5;
        Ws[k * 68 + m] = W[(size_t)(m0 + m) * EE + e0 + k];
      }
    }
    __syncthreads();
#pragma unroll
    for (int k = 0; k < 32; ++k) {
      float4 a4 = *(const float4*)&As[k * 36 + 4 * ty];
      float2 w2 = *(const float2*)&Ws[k * 68 + 2 * tx];
      acc[0][0] += a4.x * w2.x; acc[0][1] += a4.x * w2.y;
      acc[1][0] += a4.y * w2.x; acc[1][1] += a4.y * w2.y;
      acc[2][0] += a4.z * w2.x; acc[2][1] += a4.z * w2.y;
      acc[3][0] += a4.w * w2.x; acc[3][1] += a4.w * w2.y;
    }
    __syncthreads();
  }
  if (lead && ssOut) {
#pragma unroll
    for (int j = 0; j < 4; ++j) {
      float v = ssacc[j];
#pragma unroll
      for (int off = 16; off > 0; off >>= 1) v += __shfl_xor(v, off);
      if (tx == 0) atomicAdd(&ssOut[ty + 8 * j], v);
    }
  }
#pragma unroll
  for (int r = 0; r < 4; ++r) {
    float2 o = make_float2(acc[r][0], acc[r][1]);
    *(float2*)&zpart[((size_t)ks * 32 + 4 * ty + r) * mtot + m0 + 2 * tx] = o;
  }
}

// fc2-style: dest[b][n] += sum_{k in slice} y[b][k]*W2[n][k] with
// y = silu(rinv_b * sum_{s<8} zp[s][b][k] + ybias[k]).  K=4096, 16cg x 32ks.
__device__ inline void stage_fc2(int blk,
    const float* __restrict__ zp, const float* __restrict__ ssIn,
    const float* __restrict__ ybias, const float* __restrict__ W2,
    float* __restrict__ dest, float* __restrict__ As, float* __restrict__ Ws) {
  const int tid = threadIdx.x;
  const int ncg = 16, kslice = 128;
  const int cgi = blk % ncg, ks = blk / ncg;
  const int n0 = cgi * 64;
  const int tx = tid & 31, ty = tid >> 5;
  float acc[4][2] = {{0.f,0.f},{0.f,0.f},{0.f,0.f},{0.f,0.f}};
  for (int c0 = 0; c0 < kslice; c0 += 32) {
    const int k0 = ks * kslice + c0;
    {
      int idx = tid;
#pragma unroll
      for (int j = 0; j < 4; ++j, idx += 256) {
        int k = idx & 31, b = idx >> 5;
        float z = 0.f;
#pragma unroll
        for (int s = 0; s < 8; ++s)
          z += zp[((size_t)s * 32 + b) * MM + k0 + k];
        float rinv = rsqrtf(ssIn[b] * (1.f / EE) + EPSF);
        float zz = z * rinv + ybias[k0 + k];
        As[k * 36 + b] = zz / (1.f + expf(-zz));
      }
    }
    {
      int idx = tid;
#pragma unroll
      for (int j = 0; j < 8; ++j, idx += 256) {
        int k = idx & 31, m = idx >> 5;
        Ws[k * 68 + m] = W2[(size_t)(n0 + m) * MM + k0 + k];
      }
    }
    __syncthreads();
#pragma unroll
    for (int k = 0; k < 32; ++k) {
      float4 a4 = *(const float4*)&As[k * 36 + 4 * ty];
      float2 w2 = *(const float2*)&Ws[k * 68 + 2 * tx];
      acc[0][0] += a4.x * w2.x; acc[0][1] += a4.x * w2.y;
      acc[1][0] += a4.y * w2.x; acc[1][1] += a4.y * w2.y;
      acc[2][0] += a4.z * w2.x; acc[2][1] += a4.z * w2.y;
      acc[3][0] += a4.w * w2.x; acc[3][1] += a4.w * w2.y;
    }
    __syncthreads();
  }
#pragma unroll
  for (int r = 0; r < 4; ++r) {
    atomicAdd(&dest[(4 * ty + r) * EE + n0 + 2 * tx], acc[r][0]);
    atomicAdd(&dest[(4 * ty + r) * EE + n0 + 2 * tx + 1], acc[r][1]);
  }
}

__device__ inline void stage_fin(int blk,
    const float* __restrict__ zp, const float* __restrict__ ssS,
    const float* __restrict__ nb, float* __restrict__ nxt_out,
    const int* __restrict__ tokens, const float* __restrict__ embw,
    float* __restrict__ inp_next, int tnext) {
  if (blk >= 128) return;
  int e = blk * 256 + threadIdx.x;     // 0..32767
  int b = e >> 10, m = e & 1023;
  float v = 0.f;
#pragma unroll
  for (int s = 0; s < 32; ++s)
    v += zp[((size_t)s * 32 + b) * EE + m];
  float rinv = rsqrtf(ssS[b] * (1.f / EE) + EPSF);
  v = v * rinv + nb[m];
  nxt_out[e] = v;
  if (inp_next) {
    int tok = tokens[b * TT + tnext];
    inp_next[e] = embw[(size_t)tok * EE + m] + v;
  }
}

__global__ __launch_bounds__(256, 2) void k_scan(ScanParams p) {
  cg::grid_group grid = cg::this_grid();
  __shared__ __align__(16) float As[32 * 36];
  __shared__ __align__(16) float Ws[32 * 68];
  const int blk = blockIdx.x;
  // stage Z: clear ss/rowsum/aux accumulators; init inp_all[0] = emb[tok_0]
  {
    int gidx = blk * 256 + threadIdx.x;
    if (gidx < 3 * TT * BB + 2 * NROWS + 1) p.zeroBase[gidx] = 0.f;
    if (gidx < BE) {
      int b = gidx >> 10, m = gidx & 1023;
      p.inp_all[gidx] = p.embw[(size_t)p.tokens[b * TT] * EE + m];
    }
  }
  grid.sync();
  for (int t = 0; t < TT; ++t) {
    const float* inp = p.inp_all + (size_t)t * BE;
    float* s_t = p.s_all + (size_t)t * BE;
    // A: fc1 layer 0 partials (+seed hbuf, ssA)
    stage_fc1(blk, inp, p.bnw, p.fc1w, MM, 64, 8, p.zpart,
              p.ssA + t * BB, p.hbuf, nullptr, p.fc2b, As, Ws);
    grid.sync();
    // B: fc2 layer 0 -> hbuf
    stage_fc2(blk, p.zpart, p.ssA + t * BB, p.fc1b, p.fc2w, p.hbuf, As, Ws);
    grid.sync();
    // C: fc1 layer 1 partials (+seed s_t = hbuf+inp+fc2b1, ssH)
    stage_fc1(blk, p.hbuf, p.bnw + EE, p.fc1w + (size_t)MM * EE, MM, 64, 8,
              p.zpart, p.ssH + t * BB, s_t, inp, p.fc2b + EE, As, Ws);
    grid.sync();
    // D: fc2 layer 1 -> s_t
    stage_fc2(blk, p.zpart, p.ssH + t * BB, p.fc1b + MM,
              p.fc2w + (size_t)EE * MM, s_t, As, Ws);
    grid.sync();
    // E: nxt partials (ssS)
    stage_fc1(blk, s_t, p.nw, p.nxtw, EE, 16, 32, p.zpart,
              p.ssS + t * BB, nullptr, nullptr, nullptr, As, Ws);
    grid.sync();
    // F: finalize nxt + carry
    stage_fin(blk, p.zpart, p.ssS + t * BB, p.nxtb,
              p.nxt_all + (size_t)t * BE, p.tokens, p.embw,
              (t + 1 < TT) ? p.inp_all + (size_t)(t + 1) * BE : nullptr, t + 1);
    grid.sync();
  }
}

// ======================= legacy fallback (round-1, proven) =======================

__global__ void k_zero(float* __restrict__ p, int n) {
  int i = blockIdx.x * 256 + threadIdx.x;
  if (i < n) p[i] = 0.f;
}

__global__ void k_init(const int* __restrict__ tokens,
                       const float* __restrict__ embw,
                       float* __restrict__ inp0) {
  int b = blockIdx.x;
  int tok = tokens[b * TT];
  for (int e = threadIdx.x; e < EE; e += 256)
    inp0[b * EE + e] = embw[(size_t)tok * EE + e];
}

__global__ __launch_bounds__(256)
void k_fc1(const float* __restrict__ h, const float* __restrict__ bnw,
           const float* __restrict__ W, const float* __restrict__ bias,
           float* __restrict__ yout, float* __restrict__ initDst,
           const float* __restrict__ initAdd, const float* __restrict__ initBias) {
  __shared__ __align__(16) float Hs[32][68];
  __shared__ __align__(16) float Ws[8][68];
  __shared__ float ssrow[32];
  const int tid = threadIdx.x;
  const int col0 = blockIdx.x * 8;
  const int c = tid & 7;
  const int b = tid >> 3;
  const bool writer = (blockIdx.x == 0);
  float acc = 0.f;
  float ssl[8];
#pragma unroll
  for (int j = 0; j < 8; ++j) ssl[j] = 0.f;
  for (int kc = 0; kc < EE; kc += 64) {
#pragma unroll
    for (int j = 0; j < 8; ++j) {
      int i = tid + j * 256;
      int bb = i >> 6, k = i & 63;
      float v = h[bb * EE + kc + k];
      ssl[j] += v * v;
      Hs[bb][k] = v * bnw[kc + k];
      if (writer) {
        float d = v + initBias[kc + k];
        if (initAdd) d += initAdd[bb * EE + kc + k];
        initDst[bb * EE + kc + k] = d;
      }
    }
#pragma unroll
    for (int j = 0; j < 2; ++j) {
      int i = tid + j * 256;
      int cc = i >> 6, k = i & 63;
      Ws[cc][k] = W[(size_t)(col0 + cc) * EE + kc + k];
    }
    __syncthreads();
#pragma unroll
    for (int k = 0; k < 64; k += 4) {
      float4 w4 = *(const float4*)&Ws[c][k];
      float4 h4 = *(const float4*)&Hs[b][k];
      acc += h4.x * w4.x + h4.y * w4.y + h4.z * w4.z + h4.w * w4.w;
    }
    __syncthreads();
  }
  const int wv = tid >> 6;
#pragma unroll
  for (int j = 0; j < 8; ++j) {
    float v = ssl[j];
#pragma unroll
    for (int off = 32; off > 0; off >>= 1) v += __shfl_xor(v, off);
    if ((tid & 63) == 0) ssrow[wv + 4 * j] = v;
  }
  __syncthreads();
  float rinv = rsqrtf(ssrow[b] * (1.f / EE) + EPSF);
  float z = acc * rinv + bias[col0 + c];
  yout[b * MM + col0 + c] = z / (1.f + expf(-z));
}

__global__ __launch_bounds__(256)
void k_fc2(const float* __restrict__ y, const float* __restrict__ W2,
           float* __restrict__ dest) {
  __shared__ __align__(16) float Ys[32][68];
  __shared__ __align__(16) float Ws[16][68];
  const int tid = threadIdx.x;
  const int cgi = blockIdx.x & 63;
  const int ks = blockIdx.x >> 6;
  const int col0 = cgi * 16;
  const int c = tid & 15;
  const int bq = tid >> 4;
  float acc0 = 0.f, acc1 = 0.f;
  const int kend = ks * 512 + 512;
  for (int kc = ks * 512; kc < kend; kc += 64) {
#pragma unroll
    for (int j = 0; j < 8; ++j) {
      int i = tid + j * 256;
      int bb = i >> 6, k = i & 63;
      Ys[bb][k] = y[bb * MM + kc + k];
    }
#pragma unroll
    for (int j = 0; j < 4; ++j) {
      int i = tid + j * 256;
      int cc = i >> 6, k = i & 63;
      Ws[cc][k] = W2[(size_t)(col0 + cc) * MM + kc + k];
    }
    __syncthreads();
#pragma unroll
    for (int k = 0; k < 64; k += 4) {
      float4 w4 = *(const float4*)&Ws[c][k];
      float4 a4 = *(const float4*)&Ys[bq][k];
      float4 b4 = *(const float4*)&Ys[bq + 16][k];
      acc0 += a4.x * w4.x + a4.y * w4.y + a4.z * w4.z + a4.w * w4.w;
      acc1 += b4.x * w4.x + b4.y * w4.y + b4.z * w4.z + b4.w * w4.w;
    }
    __syncthreads();
  }
  atomicAdd(&dest[bq * EE + col0 + c], acc0);
  atomicAdd(&dest[(bq + 16) * EE + col0 + c], acc1);
}

__global__ __launch_bounds__(256)
void k_nxt(const float* __restrict__ s, const float* __restrict__ nw,
           const float* __restrict__ Wn, const float* __restrict__ nb,
           float* __restrict__ nxt_out, float* __restrict__ ss_out,
           const int* __restrict__ tokens, const float* __restrict__ embw,
           float* __restrict__ inp_next, int tnext) {
  __shared__ __align__(16) float Xs[32][68];
  __shared__ __align__(16) float Ws[8][68];
  __shared__ float ssrow[32];
  const int tid = threadIdx.x;
  const int col0 = blockIdx.x * 8;
  const int c = tid & 7;
  const int b = tid >> 3;
  float acc = 0.f;
  float ssl[8];
#pragma unroll
  for (int j = 0; j < 8; ++j) ssl[j] = 0.f;
  for (int kc = 0; kc < EE; kc += 64) {
#pragma unroll
    for (int j = 0; j < 8; ++j) {
      int i = tid + j * 256;
      int bb = i >> 6, k = i & 63;
      float v = s[bb * EE + kc + k];
      ssl[j] += v * v;
      Xs[bb][k] = v * nw[kc + k];
    }
#pragma unroll
    for (int j = 0; j < 2; ++j) {
      int i = tid + j * 256;
      int cc = i >> 6, k = i & 63;
      Ws[cc][k] = Wn[(size_t)(col0 + cc) * EE + kc + k];
    }
    __syncthreads();
#pragma unroll
    for (int k = 0; k < 64; k += 4) {
      float4 w4 = *(const float4*)&Ws[c][k];
      float4 h4 = *(const float4*)&Xs[b][k];
      acc += h4.x * w4.x + h4.y * w4.y + h4.z * w4.z + h4.w * w4.w;
    }
    __syncthreads();
  }
  const int wv = tid >> 6;
#pragma unroll
  for (int j = 0; j < 8; ++j) {
    float v = ssl[j];
#pragma unroll
    for (int off = 32; off > 0; off >>= 1) v += __shfl_xor(v, off);
    if ((tid & 63) == 0) {
      ssrow[wv + 4 * j] = v;
      if (blockIdx.x == 0) ss_out[wv + 4 * j] = v;
    }
  }
  __syncthreads();
  float rinv = rsqrtf(ssrow[b] * (1.f / EE) + EPSF);
  float nv = acc * rinv + nb[col0 + c];
  nxt_out[b * EE + col0 + c] = nv;
  if (inp_next) {
    int tok = tokens[b * TT + tnext];
    inp_next[b * EE + col0 + c] = embw[(size_t)tok * EE + col0 + c] + nv;
  }
}

// ======================= phase 2 (shared) =======================

__global__ __launch_bounds__(256)
void k_curemb(const float* __restrict__ s_all, const float* __restrict__ ss_s,
              const float* __restrict__ nw, const float* __restrict__ Wc,
              const float* __restrict__ cb, const float* __restrict__ inp_all,
              float* __restrict__ cur_out, float* __restrict__ aux_accum) {
  __shared__ __align__(16) float As[16][68];
  __shared__ __align__(16) float Bs[16][68];
  __shared__ float rr[64];
  __shared__ float wred[4];
  const int tid = threadIdx.x;
  const int rt = blockIdx.x & 127;
  const int ct = blockIdx.x >> 7;
  const int row0 = rt * 64, col0 = ct * 64;
  if (tid < 64) rr[tid] = rsqrtf(ss_s[row0 + tid] * (1.f / EE) + EPSF);
  __syncthreads();
  float acc[4][4];
#pragma unroll
  for (int i = 0; i < 4; ++i)
#pragma unroll
    for (int j = 0; j < 4; ++j) acc[i][j] = 0.f;
  const int tx = tid & 15, ty = tid >> 4;
  for (int kc = 0; kc < EE; kc += 16) {
#pragma unroll
    for (int j = 0; j < 4; ++j) {
      int i = tid + j * 256;
      int k = i & 15, m = i >> 4;
      As[k][m] = s_all[(size_t)(row0 + m) * EE + kc + k] * rr[m] * nw[kc + k];
      Bs[k][m] = Wc[(size_t)(col0 + m) * EE + kc + k];
    }
    __syncthreads();
#pragma unroll
    for (int k = 0; k < 16; ++k) {
      float4 a4 = *(const float4*)&As[k][tx * 4];
      float4 b4 = *(const float4*)&Bs[k][ty * 4];
      acc[0][0] += a4.x*b4.x; acc[0][1] += a4.x*b4.y; acc[0][2] += a4.x*b4.z; acc[0][3] += a4.x*b4.w;
      acc[1][0] += a4.y*b4.x; acc[1][1] += a4.y*b4.y; acc[1][2] += a4.y*b4.z; acc[1][3] += a4.y*b4.w;
      acc[2][0] += a4.z*b4.x; acc[2][1] += a4.z*b4.y; acc[2][2] += a4.z*b4.z; acc[2][3] += a4.z*b4.w;
      acc[3][0] += a4.w*b4.x; acc[3][1] += a4.w*b4.y; acc[3][2] += a4.w*b4.z; acc[3][3] += a4.w*b4.w;
    }
    __syncthreads();
  }
  float auxp = 0.f;
#pragma unroll
  for (int i = 0; i < 4; ++i) {
    int r = row0 + tx * 4 + i;
#pragma unroll
    for (int j = 0; j < 4; ++j) {
      int col = col0 + ty * 4 + j;
      float v = acc[i][j] + cb[col];
      cur_out[(size_t)r * EE + col] = v;
      float d = v - inp_all[(size_t)r * EE + col];
      auxp += d * d;
    }
  }
#pragma unroll
  for (int off = 32; off > 0; off >>= 1) auxp += __shfl_xor(auxp, off);
  if ((tid & 63) == 0) wred[tid >> 6] = auxp;
  __syncthreads();
  if (tid == 0) atomicAdd(aux_accum, wred[0] + wred[1] + wred[2] + wred[3]);
}

__global__ __launch_bounds__(256)
void k_logits(const float* __restrict__ A, const float* __restrict__ embw,
              const int* __restrict__ idxs, float* __restrict__ rowsum,
              float* __restrict__ lidx, float* __restrict__ store) {
  __shared__ __align__(16) float As[16][68];
  __shared__ __align__(16) float Bs[16][68];
  __shared__ float rowpart[64];
  const int tid = threadIdx.x;
  const int rt = blockIdx.x & 127;
  const int ct = blockIdx.x >> 7;
  const int row0 = rt * 64, col0 = ct * 64;
  float acc[4][4];
#pragma unroll
  for (int i = 0; i < 4; ++i)
#pragma unroll
    for (int j = 0; j < 4; ++j) acc[i][j] = 0.f;
  const int tx = tid & 15, ty = tid >> 4;
  for (int kc = 0; kc < EE; kc += 16) {
#pragma unroll
    for (int j = 0; j < 4; ++j) {
      int i = tid + j * 256;
      int k = i & 15, m = i >> 4;
      As[k][m] = A[(size_t)(row0 + m) * EE + kc + k];
      Bs[k][m] = embw[(size_t)(col0 + m) * EE + kc + k];
    }
    __syncthreads();
#pragma unroll
    for (int k = 0; k < 16; ++k) {
      float4 a4 = *(const float4*)&As[k][tx * 4];
      float4 b4 = *(const float4*)&Bs[k][ty * 4];
      acc[0][0] += a4.x*b4.x; acc[0][1] += a4.x*b4.y; acc[0][2] += a4.x*b4.z; acc[0][3] += a4.x*b4.w;
      acc[1][0] += a4.y*b4.x; acc[1][1] += a4.y*b4.y; acc[1][2] += a4.y*b4.z; acc[1][3] += a4.y*b4.w;
      acc[2][0] += a4.z*b4.x; acc[2][1] += a4.z*b4.y; acc[2][2] += a4.z*b4.z; acc[2][3] += a4.z*b4.w;
      acc[3][0] += a4.w*b4.x; acc[3][1] += a4.w*b4.y; acc[3][2] += a4.w*b4.z; acc[3][3] += a4.w*b4.w;
    }
    __syncthreads();
  }
  if (tid < 64) rowpart[tid] = 0.f;
  __syncthreads();
#pragma unroll
  for (int i = 0; i < 4; ++i) {
    int r = row0 + tx * 4 + i;
    int t = r >> 5, bb = r & 31;
    int idx = idxs[bb * TT + t];
    float e0 = expf(acc[i][0]);
    float e1 = expf(acc[i][1]);
    float e2 = expf(acc[i][2]);
    float e3 = expf(acc[i][3]);
    atomicAdd(&rowpart[tx * 4 + i], e0 + e1 + e2 + e3);
    int cbase = col0 + ty * 4;
#pragma unroll
    for (int j = 0; j < 4; ++j)
      if (cbase + j == idx) lidx[r] = acc[i][j];
    if (store) {
      float4 o = make_float4(acc[i][0], acc[i][1], acc[i][2], acc[i][3]);
      *(float4*)(store + ((size_t)bb * TT + t) * VV + cbase) = o;
    }
  }
  __syncthreads();
  if (tid < 64) atomicAdd(&rowsum[row0 + tid], rowpart[tid]);
}

__global__ void k_final(const float* __restrict__ rs_cur,
                        const float* __restrict__ rs_nxt,
                        const float* __restrict__ ltok,
                        const float* __restrict__ ltgt,
                        const float* __restrict__ aux_accum,
                        float* __restrict__ out) {
  float p = 0.f;
  for (int r = threadIdx.x; r < NROWS; r += 256)
    p += (ltok[r] - logf(rs_cur[r])) + (ltgt[r] - logf(rs_nxt[r]));
#pragma unroll
  for (int off = 32; off > 0; off >>= 1) p += __shfl_xor(p, off);
  __shared__ float w[4];
  if ((threadIdx.x & 63) == 0) w[threadIdx.x >> 6] = p;
  __syncthreads();
  if (threadIdx.x == 0) {
    float tot = w[0] + w[1] + w[2] + w[3];
    out[0] = -tot / (2.f * (float)NROWS);
    out[1] = aux_accum[0] * (1.f / ((float)NROWS * EE));
  }
}

// ======================= launch =======================

extern "C" void kernel_launch(void* const* d_in, const int* in_sizes, int n_in,
                              void* d_out, int out_size, void* d_ws, size_t ws_size,
                              hipStream_t stream) {
  (void)in_sizes; (void)n_in; (void)out_size; (void)ws_size;
  const int*   tokens  = (const int*)d_in[0];
  const int*   targets = (const int*)d_in[1];
  const float* embw    = (const float*)d_in[2];
  const float* bnw     = (const float*)d_in[3];
  const float* fc1w    = (const float*)d_in[4];
  const float* fc1b    = (const float*)d_in[5];
  const float* fc2w    = (const float*)d_in[6];
  const float* fc2b    = (const float*)d_in[7];
  const float* nw      = (const float*)d_in[8];
  const float* curw    = (const float*)d_in[9];
  const float* curb    = (const float*)d_in[10];
  const float* nxtw    = (const float*)d_in[11];
  const float* nxtb    = (const float*)d_in[12];
  float* out = (float*)d_out;

  // d_out doubles as scratch for three [8192][1024] fp32 activations; the
  // final logits GEMM overwrites all of it with the real output.
  float* cur_all = out;
  float* s_all   = out + (size_t)NROWS * EE;
  float* inp_all = out + 2 * (size_t)NROWS * EE;

  float* ws      = (float*)d_ws;
  float* nxt_all = ws;                                   // 8,388,608
  float* zpart   = nxt_all + (size_t)NROWS * EE;         // 1,048,576
  float* hbuf    = zpart + 1048576;                      // 32,768
  float* ssA     = hbuf + BE;                            // 8,192
  float* ssH     = ssA + TT * BB;                        // 8,192
  float* ssS     = ssH + TT * BB;                        // 8,192
  float* rs_cur  = ssS + TT * BB;                        // 8,192
  float* rs_nxt  = rs_cur + NROWS;                       // 8,192
  float* auxac   = rs_nxt + NROWS;                       // 1
  float* ltok    = auxac + 1;                            // 8,192
  float* ltgt    = ltok + NROWS;                         // 8,192
  float* ybuf    = ltgt + NROWS;                         // 131,072 (legacy)

  ScanParams p;
  p.tokens = tokens; p.embw = embw; p.bnw = bnw;
  p.fc1w = fc1w; p.fc1b = fc1b; p.fc2w = fc2w; p.fc2b = fc2b;
  p.nw = nw; p.nxtw = nxtw; p.nxtb = nxtb;
  p.inp_all = inp_all; p.s_all = s_all; p.nxt_all = nxt_all;
  p.zpart = zpart; p.hbuf = hbuf;
  p.ssA = ssA; p.ssH = ssH; p.ssS = ssS;
  p.zeroBase = ssA;  // clears ssA,ssH,ssS,rs_cur,rs_nxt,auxac contiguously

  void* args[] = { &p };
  hipError_t err = hipLaunchCooperativeKernel((const void*)k_scan,
                                              dim3(512), dim3(256),
                                              args, 0, stream);
  if (err != hipSuccess) {
    // Fallback: proven round-1 multi-kernel sequence.
    k_zero<<<(2 * NROWS + 1 + 255) / 256, 256, 0, stream>>>(rs_cur, 2 * NROWS + 1);
    k_init<<<32, 256, 0, stream>>>(tokens, embw, inp_all);
    for (int t = 0; t < TT; ++t) {
      const float* inp = inp_all + (size_t)t * BE;
      float* s = s_all + (size_t)t * BE;
      k_fc1<<<512, 256, 0, stream>>>(inp, bnw, fc1w, fc1b, ybuf,
                                     hbuf, nullptr, fc2b);
      k_fc2<<<512, 256, 0, stream>>>(ybuf, fc2w, hbuf);
      k_fc1<<<512, 256, 0, stream>>>(hbuf, bnw + EE, fc1w + (size_t)MM * EE,
                                     fc1b + MM, ybuf, s, inp, fc2b + EE);
      k_fc2<<<512, 256, 0, stream>>>(ybuf, fc2w + (size_t)EE * MM, s);
      k_nxt<<<128, 256, 0, stream>>>(s, nw, nxtw, nxtb,
                                     nxt_all + (size_t)t * BE, ssS + t * BB,
                                     tokens, embw,
                                     (t + 1 < TT) ? inp_all + (size_t)(t + 1) * BE : nullptr,
                                     t + 1);
    }
  }

  k_curemb<<<2048, 256, 0, stream>>>(s_all, ssS, nw, curw, curb, inp_all,
                                     cur_all, auxac);
  k_logits<<<8192, 256, 0, stream>>>(cur_all, embw, tokens, rs_cur, ltok, nullptr);
  k_logits<<<8192, 256, 0, stream>>>(nxt_all, embw, targets, rs_nxt, ltgt, out);
  k_final<<<1, 256, 0, stream>>>(rs_cur, rs_nxt, ltok, ltgt, auxac,
                                 out + (size_t)NROWS * VV);
}

// Round 3
// 61068.805 us; speedup vs baseline: 1.8746x; 1.8746x over previous
//
#include <hip/hip_runtime.h>
#include <math.h>

// Problem constants (fixed by setup_inputs)
#define TT  256   // scan steps
#define BB  32    // batch
#define EE  1024  // embed dim
#define MM  4096  // mlp dim
#define VV  4096  // vocab
#define BE  (BB*EE)      // 32768
#define NROWS (TT*BB)    // 8192
#define EPSF 1.1920929e-07f

// ======================= custom grid barrier =======================
// One fresh counter per barrier (no reset, no generation races). Counters
// zeroed by k_zero before the cooperative launch. Arrive-and-poll by
// thread 0 of each real block; agent-scope fences give cross-XCD visibility.
__device__ inline void gbar(unsigned* cnt, int idx, unsigned nblk) {
  __syncthreads();
  if (threadIdx.x == 0) {
    __builtin_amdgcn_fence(__ATOMIC_RELEASE, "agent");
    __hip_atomic_fetch_add(&cnt[idx], 1u, __ATOMIC_RELAXED,
                           __HIP_MEMORY_SCOPE_AGENT);
    while (__hip_atomic_load(&cnt[idx], __ATOMIC_RELAXED,
                             __HIP_MEMORY_SCOPE_AGENT) < nblk)
      __builtin_amdgcn_s_sleep(1);
    __builtin_amdgcn_fence(__ATOMIC_ACQUIRE, "agent");
  }
  __syncthreads();
}

// ======================= scan stages (round-2 verified tiling) =======================
// vblk = virtual 256-thread block (2 per real 512-thread block).

struct ScanParams {
  const int* tokens;
  const float* embw;
  const float* bnw;
  const float* fc1w;
  const float* fc1b;
  const float* fc2w;
  const float* fc2b;
  const float* nw;
  const float* nxtw;
  const float* nxtb;
  float* inp_all;   // [TT][32][EE] (in d_out)
  float* s_all;     // [TT][32][EE] (in d_out)
  float* nxt_all;   // [TT][32][EE] (ws)
  float* zpart;     // [8][32][4096] (ws)
  float* hbuf;      // [32][EE]
  float* ssA;       // [TT][32]
  float* ssH;       // [TT][32]
  float* ssS;       // [TT][32]
  unsigned* cnt;    // barrier counters
};

// fc1-style partial GEMM: zpart[ks][b][m] = sum_{e in slice} a[b][e]*scl[e]*W[m][e].
// 64 colgroups x 8 kslices = 512 vblks; tile 32 rows x 64 cols, 4x2/thread.
// ks-lead blocks (cgi==0) atomicAdd row sum-squares and optionally seed
// seedDst = a + seedBias (+ seedAdd) over their e-slice.
__device__ inline void stage_fc1(int vblk, int tid,
    const float* __restrict__ a, const float* __restrict__ scl,
    const float* __restrict__ W,
    float* __restrict__ zpart, float* __restrict__ ssOut,
    float* __restrict__ seedDst, const float* __restrict__ seedAdd,
    const float* __restrict__ seedBias,
    float* __restrict__ As, float* __restrict__ Ws) {
  const int cgi = vblk & 63, ks = vblk >> 6;   // 64 cg x 8 ks
  const int e0base = ks * 128;                 // e-slice of 128
  const int tx = tid & 31, ty = tid >> 5;
  const int m0 = cgi * 64;
  float acc[4][2] = {{0.f,0.f},{0.f,0.f},{0.f,0.f},{0.f,0.f}};
  float ssacc[4] = {0.f,0.f,0.f,0.f};
  const bool lead = (cgi == 0);
  for (int c0 = 0; c0 < 128; c0 += 32) {
    const int e0 = e0base + c0;
    {
      int idx = tid;
#pragma unroll
      for (int j = 0; j < 4; ++j, idx += 256) {
        int k = idx & 31, b = idx >> 5;
        float v = a[b * EE + e0 + k];
        ssacc[j] += v * v;
        As[k * 36 + b] = v * scl[e0 + k];
        if (lead && seedDst) {
          float d = v + seedBias[e0 + k];
          if (seedAdd) d += seedAdd[b * EE + e0 + k];
          seedDst[b * EE + e0 + k] = d;
        }
      }
    }
    {
      int idx = tid;
#pragma unroll
      for (int j = 0; j < 8; ++j, idx += 256) {
        int k = idx & 31, m = idx >> 5;
        Ws[k * 68 + m] = W[(size_t)(m0 + m) * EE + e0 + k];
      }
    }
    __syncthreads();
#pragma unroll
    for (int k = 0; k < 32; ++k) {
      float4 a4 = *(const float4*)&As[k * 36 + 4 * ty];
      float2 w2 = *(const float2*)&Ws[k * 68 + 2 * tx];
      acc[0][0] += a4.x * w2.x; acc[0][1] += a4.x * w2.y;
      acc[1][0] += a4.y * w2.x; acc[1][1] += a4.y * w2.y;
      acc[2][0] += a4.z * w2.x; acc[2][1] += a4.z * w2.y;
      acc[3][0] += a4.w * w2.x; acc[3][1] += a4.w * w2.y;
    }
    __syncthreads();
  }
  if (lead && ssOut) {
#pragma unroll
    for (int j = 0; j < 4; ++j) {
      float v = ssacc[j];
#pragma unroll
      for (int off = 16; off > 0; off >>= 1) v += __shfl_xor(v, off);
      if (tx == 0) atomicAdd(&ssOut[ty + 8 * j], v);
    }
  }
#pragma unroll
  for (int r = 0; r < 4; ++r) {
    float2 o = make_float2(acc[r][0], acc[r][1]);
    *(float2*)&zpart[((size_t)ks * 32 + 4 * ty + r) * MM + m0 + 2 * tx] = o;
  }
}

// fc2-style: dest[b][n] += sum_{k in slice} y[b][k]*W2[n][k],
// y = silu(rinv_b * sum_{s<8} zp[s][b][k] + ybias[k]). 16cg x 32ks = 512 vblks.
__device__ inline void stage_fc2(int vblk, int tid,
    const float* __restrict__ zp, const float* __restrict__ ssIn,
    const float* __restrict__ ybias, const float* __restrict__ W2,
    float* __restrict__ dest, float* __restrict__ As, float* __restrict__ Ws) {
  const int cgi = vblk & 15, ks = vblk >> 4;   // 16 cg x 32 ks
  const int n0 = cgi * 64;
  const int tx = tid & 31, ty = tid >> 5;
  float acc[4][2] = {{0.f,0.f},{0.f,0.f},{0.f,0.f},{0.f,0.f}};
  for (int c0 = 0; c0 < 128; c0 += 32) {
    const int k0 = ks * 128 + c0;
    {
      int idx = tid;
#pragma unroll
      for (int j = 0; j < 4; ++j, idx += 256) {
        int k = idx & 31, b = idx >> 5;
        float z = 0.f;
#pragma unroll
        for (int s = 0; s < 8; ++s)
          z += zp[((size_t)s * 32 + b) * MM + k0 + k];
        float rinv = rsqrtf(ssIn[b] * (1.f / EE) + EPSF);
        float zz = z * rinv + ybias[k0 + k];
        As[k * 36 + b] = zz / (1.f + expf(-zz));
      }
    }
    {
      int idx = tid;
#pragma unroll
      for (int j = 0; j < 8; ++j, idx += 256) {
        int k = idx & 31, m = idx >> 5;
        Ws[k * 68 + m] = W2[(size_t)(n0 + m) * MM + k0 + k];
      }
    }
    __syncthreads();
#pragma unroll
    for (int k = 0; k < 32; ++k) {
      float4 a4 = *(const float4*)&As[k * 36 + 4 * ty];
      float2 w2 = *(const float2*)&Ws[k * 68 + 2 * tx];
      acc[0][0] += a4.x * w2.x; acc[0][1] += a4.x * w2.y;
      acc[1][0] += a4.y * w2.x; acc[1][1] += a4.y * w2.y;
      acc[2][0] += a4.z * w2.x; acc[2][1] += a4.z * w2.y;
      acc[3][0] += a4.w * w2.x; acc[3][1] += a4.w * w2.y;
    }
    __syncthreads();
  }
#pragma unroll
  for (int r = 0; r < 4; ++r) {
    atomicAdd(&dest[(4 * ty + r) * EE + n0 + 2 * tx], acc[r][0]);
    atomicAdd(&dest[(4 * ty + r) * EE + n0 + 2 * tx + 1], acc[r][1]);
  }
}

// nxt GEMM, full-K (merged partial+finalize): 64 active vblks x 16 cols.
// Each active vblk stages the full s row-block, computes its own ss (rinv),
// writes nxt and the carry inp_{t+1} = emb[tok] + nxt. vblk 0 persists raw ss.
__device__ inline void stage_nxt(int vblk, int tid,
    const float* __restrict__ s, const float* __restrict__ nw,
    const float* __restrict__ Wn, const float* __restrict__ nb,
    float* __restrict__ nxt_out, float* __restrict__ ss_out,
    const int* __restrict__ tokens, const float* __restrict__ embw,
    float* __restrict__ inp_next, int tnext,
    float* __restrict__ Wt /*16x68 in As*/, float* __restrict__ Xs /*32x68 in Ws*/,
    float* __restrict__ ssrow /*32*/) {
  const bool act = (vblk < 64);
  const int col0 = vblk * 16;
  const int c = tid & 15;
  const int b = tid >> 4;            // 0..15 -> rows b, b+16
  float acc0 = 0.f, acc1 = 0.f;
  float ssl[8] = {0.f,0.f,0.f,0.f,0.f,0.f,0.f,0.f};
  for (int kc = 0; kc < EE; kc += 64) {
    if (act) {
      int idx = tid;
#pragma unroll
      for (int j = 0; j < 8; ++j, idx += 256) {
        int k = idx & 63, bb = idx >> 6;   // bb = tid>>6 + 4j
        float v = s[bb * EE + kc + k];
        ssl[j] += v * v;
        Xs[bb * 68 + k] = v * nw[kc + k];
      }
      idx = tid;
#pragma unroll
      for (int j = 0; j < 4; ++j, idx += 256) {
        int k = idx & 63, cc = idx >> 6;   // cc = tid>>6 + 4j (0..15)
        Wt[cc * 68 + k] = Wn[(size_t)(col0 + cc) * EE + kc + k];
      }
    }
    __syncthreads();
    if (act) {
#pragma unroll
      for (int k = 0; k < 64; k += 4) {
        float4 w4 = *(const float4*)&Wt[c * 68 + k];
        float4 x0 = *(const float4*)&Xs[b * 68 + k];
        float4 x1 = *(const float4*)&Xs[(b + 16) * 68 + k];
        acc0 += x0.x * w4.x + x0.y * w4.y + x0.z * w4.z + x0.w * w4.w;
        acc1 += x1.x * w4.x + x1.y * w4.y + x1.z * w4.z + x1.w * w4.w;
      }
    }
    __syncthreads();
  }
  // wave wv staged rows {wv+4j}; reduce over the 64 lanes of each wave
  if (act) {
    const int wv = tid >> 6;
#pragma unroll
    for (int j = 0; j < 8; ++j) {
      float v = ssl[j];
#pragma unroll
      for (int off = 32; off > 0; off >>= 1) v += __shfl_xor(v, off);
      if ((tid & 63) == 0) ssrow[wv + 4 * j] = v;
    }
  }
  __syncthreads();
  if (act) {
    float rinv0 = rsqrtf(ssrow[b] * (1.f / EE) + EPSF);
    float rinv1 = rsqrtf(ssrow[b + 16] * (1.f / EE) + EPSF);
    float nv0 = acc0 * rinv0 + nb[col0 + c];
    float nv1 = acc1 * rinv1 + nb[col0 + c];
    nxt_out[b * EE + col0 + c] = nv0;
    nxt_out[(b + 16) * EE + col0 + c] = nv1;
    if (inp_next) {
      int tok0 = tokens[b * TT + tnext];
      int tok1 = tokens[(b + 16) * TT + tnext];
      inp_next[b * EE + col0 + c] = embw[(size_t)tok0 * EE + col0 + c] + nv0;
      inp_next[(b + 16) * EE + col0 + c] = embw[(size_t)tok1 * EE + col0 + c] + nv1;
    }
    if (vblk == 0 && tid < 32) ss_out[tid] = ssrow[tid];
  }
  __syncthreads();
}

__global__ __launch_bounds__(512, 1) void k_scan2(ScanParams p) {
  __shared__ __align__(16) float AsB[2][32 * 36];
  __shared__ __align__(16) float WsB[2][32 * 68];
  __shared__ float ssrowB[2][32];
  const int sub = threadIdx.x >> 8;
  const int tid = threadIdx.x & 255;
  const int vblk = blockIdx.x * 2 + sub;
  float* As = AsB[sub];
  float* Ws = WsB[sub];
  int sidx = 0;
  for (int t = 0; t < TT; ++t) {
    const float* inp = p.inp_all + (size_t)t * BE;
    float* s_t = p.s_all + (size_t)t * BE;
    // A: fc1 layer-0 partials (+seed hbuf = inp+fc2b0, ssA)
    stage_fc1(vblk, tid, inp, p.bnw, p.fc1w, p.zpart,
              p.ssA + t * BB, p.hbuf, nullptr, p.fc2b, As, Ws);
    gbar(p.cnt, sidx++, 256);
    // B: fc2 layer 0 -> hbuf (seeded atomics)
    stage_fc2(vblk, tid, p.zpart, p.ssA + t * BB, p.fc1b, p.fc2w, p.hbuf, As, Ws);
    gbar(p.cnt, sidx++, 256);
    // C: fc1 layer-1 partials (+seed s_t = hbuf+inp+fc2b1, ssH)
    stage_fc1(vblk, tid, p.hbuf, p.bnw + EE, p.fc1w + (size_t)MM * EE,
              p.zpart, p.ssH + t * BB, s_t, inp, p.fc2b + EE, As, Ws);
    gbar(p.cnt, sidx++, 256);
    // D: fc2 layer 1 -> s_t (seeded atomics)
    stage_fc2(vblk, tid, p.zpart, p.ssH + t * BB, p.fc1b + MM,
              p.fc2w + (size_t)EE * MM, s_t, As, Ws);
    gbar(p.cnt, sidx++, 256);
    // E: nxt GEMM full-K + finalize carry (merged)
    stage_nxt(vblk, tid, s_t, p.nw, p.nxtw, p.nxtb,
              p.nxt_all + (size_t)t * BE, p.ssS + t * BB,
              p.tokens, p.embw,
              (t + 1 < TT) ? p.inp_all + (size_t)(t + 1) * BE : nullptr,
              t + 1, As, Ws, ssrowB[sub]);
    gbar(p.cnt, sidx++, 256);
  }
}

// ======================= small helpers =======================

__global__ void k_zero(float* __restrict__ p, int n) {
  int i = blockIdx.x * 256 + threadIdx.x;
  if (i < n) p[i] = 0.f;
}

__global__ void k_init(const int* __restrict__ tokens,
                       const float* __restrict__ embw,
                       float* __restrict__ inp0) {
  int b = blockIdx.x;
  int tok = tokens[b * TT];
  for (int e = threadIdx.x; e < EE; e += 256)
    inp0[b * EE + e] = embw[(size_t)tok * EE + e];
}

// ======================= legacy fallback (round-1, proven) =======================

__global__ __launch_bounds__(256)
void k_fc1(const float* __restrict__ h, const float* __restrict__ bnw,
           const float* __restrict__ W, const float* __restrict__ bias,
           float* __restrict__ yout, float* __restrict__ initDst,
           const float* __restrict__ initAdd, const float* __restrict__ initBias) {
  __shared__ __align__(16) float Hs[32][68];
  __shared__ __align__(16) float Ws[8][68];
  __shared__ float ssrow[32];
  const int tid = threadIdx.x;
  const int col0 = blockIdx.x * 8;
  const int c = tid & 7;
  const int b = tid >> 3;
  const bool writer = (blockIdx.x == 0);
  float acc = 0.f;
  float ssl[8];
#pragma unroll
  for (int j = 0; j < 8; ++j) ssl[j] = 0.f;
  for (int kc = 0; kc < EE; kc += 64) {
#pragma unroll
    for (int j = 0; j < 8; ++j) {
      int i = tid + j * 256;
      int bb = i >> 6, k = i & 63;
      float v = h[bb * EE + kc + k];
      ssl[j] += v * v;
      Hs[bb][k] = v * bnw[kc + k];
      if (writer) {
        float d = v + initBias[kc + k];
        if (initAdd) d += initAdd[bb * EE + kc + k];
        initDst[bb * EE + kc + k] = d;
      }
    }
#pragma unroll
    for (int j = 0; j < 2; ++j) {
      int i = tid + j * 256;
      int cc = i >> 6, k = i & 63;
      Ws[cc][k] = W[(size_t)(col0 + cc) * EE + kc + k];
    }
    __syncthreads();
#pragma unroll
    for (int k = 0; k < 64; k += 4) {
      float4 w4 = *(const float4*)&Ws[c][k];
      float4 h4 = *(const float4*)&Hs[b][k];
      acc += h4.x * w4.x + h4.y * w4.y + h4.z * w4.z + h4.w * w4.w;
    }
    __syncthreads();
  }
  const int wv = tid >> 6;
#pragma unroll
  for (int j = 0; j < 8; ++j) {
    float v = ssl[j];
#pragma unroll
    for (int off = 32; off > 0; off >>= 1) v += __shfl_xor(v, off);
    if ((tid & 63) == 0) ssrow[wv + 4 * j] = v;
  }
  __syncthreads();
  float rinv = rsqrtf(ssrow[b] * (1.f / EE) + EPSF);
  float z = acc * rinv + bias[col0 + c];
  yout[b * MM + col0 + c] = z / (1.f + expf(-z));
}

__global__ __launch_bounds__(256)
void k_fc2(const float* __restrict__ y, const float* __restrict__ W2,
           float* __restrict__ dest) {
  __shared__ __align__(16) float Ys[32][68];
  __shared__ __align__(16) float Ws[16][68];
  const int tid = threadIdx.x;
  const int cgi = blockIdx.x & 63;
  const int ks = blockIdx.x >> 6;
  const int col0 = cgi * 16;
  const int c = tid & 15;
  const int bq = tid >> 4;
  float acc0 = 0.f, acc1 = 0.f;
  const int kend = ks * 512 + 512;
  for (int kc = ks * 512; kc < kend; kc += 64) {
#pragma unroll
    for (int j = 0; j < 8; ++j) {
      int i = tid + j * 256;
      int bb = i >> 6, k = i & 63;
      Ys[bb][k] = y[bb * MM + kc + k];
    }
#pragma unroll
    for (int j = 0; j < 4; ++j) {
      int i = tid + j * 256;
      int cc = i >> 6, k = i & 63;
      Ws[cc][k] = W2[(size_t)(col0 + cc) * MM + kc + k];
    }
    __syncthreads();
#pragma unroll
    for (int k = 0; k < 64; k += 4) {
      float4 w4 = *(const float4*)&Ws[c][k];
      float4 a4 = *(const float4*)&Ys[bq][k];
      float4 b4 = *(const float4*)&Ys[bq + 16][k];
      acc0 += a4.x * w4.x + a4.y * w4.y + a4.z * w4.z + a4.w * w4.w;
      acc1 += b4.x * w4.x + b4.y * w4.y + b4.z * w4.z + b4.w * w4.w;
    }
    __syncthreads();
  }
  atomicAdd(&dest[bq * EE + col0 + c], acc0);
  atomicAdd(&dest[(bq + 16) * EE + col0 + c], acc1);
}

__global__ __launch_bounds__(256)
void k_nxt(const float* __restrict__ s, const float* __restrict__ nw,
           const float* __restrict__ Wn, const float* __restrict__ nb,
           float* __restrict__ nxt_out, float* __restrict__ ss_out,
           const int* __restrict__ tokens, const float* __restrict__ embw,
           float* __restrict__ inp_next, int tnext) {
  __shared__ __align__(16) float Xs[32][68];
  __shared__ __align__(16) float Ws[8][68];
  __shared__ float ssrow[32];
  const int tid = threadIdx.x;
  const int col0 = blockIdx.x * 8;
  const int c = tid & 7;
  const int b = tid >> 3;
  float acc = 0.f;
  float ssl[8];
#pragma unroll
  for (int j = 0; j < 8; ++j) ssl[j] = 0.f;
  for (int kc = 0; kc < EE; kc += 64) {
#pragma unroll
    for (int j = 0; j < 8; ++j) {
      int i = tid + j * 256;
      int bb = i >> 6, k = i & 63;
      float v = s[bb * EE + kc + k];
      ssl[j] += v * v;
      Xs[bb][k] = v * nw[kc + k];
    }
#pragma unroll
    for (int j = 0; j < 2; ++j) {
      int i = tid + j * 256;
      int cc = i >> 6, k = i & 63;
      Ws[cc][k] = Wn[(size_t)(col0 + cc) * EE + kc + k];
    }
    __syncthreads();
#pragma unroll
    for (int k = 0; k < 64; k += 4) {
      float4 w4 = *(const float4*)&Ws[c][k];
      float4 h4 = *(const float4*)&Xs[b][k];
      acc += h4.x * w4.x + h4.y * w4.y + h4.z * w4.z + h4.w * w4.w;
    }
    __syncthreads();
  }
  const int wv = tid >> 6;
#pragma unroll
  for (int j = 0; j < 8; ++j) {
    float v = ssl[j];
#pragma unroll
    for (int off = 32; off > 0; off >>= 1) v += __shfl_xor(v, off);
    if ((tid & 63) == 0) {
      ssrow[wv + 4 * j] = v;
      if (blockIdx.x == 0) ss_out[wv + 4 * j] = v;
    }
  }
  __syncthreads();
  float rinv = rsqrtf(ssrow[b] * (1.f / EE) + EPSF);
  float nv = acc * rinv + nb[col0 + c];
  nxt_out[b * EE + col0 + c] = nv;
  if (inp_next) {
    int tok = tokens[b * TT + tnext];
    inp_next[b * EE + col0 + c] = embw[(size_t)tok * EE + col0 + c] + nv;
  }
}

// ======================= phase 2 =======================

__global__ __launch_bounds__(256)
void k_curemb(const float* __restrict__ s_all, const float* __restrict__ ss_s,
              const float* __restrict__ nw, const float* __restrict__ Wc,
              const float* __restrict__ cb, const float* __restrict__ inp_all,
              float* __restrict__ cur_out, float* __restrict__ aux_accum) {
  __shared__ __align__(16) float As[16][68];
  __shared__ __align__(16) float Bs[16][68];
  __shared__ float rr[64];
  __shared__ float wred[4];
  const int tid = threadIdx.x;
  const int rt = blockIdx.x & 127;
  const int ct = blockIdx.x >> 7;
  const int row0 = rt * 64, col0 = ct * 64;
  if (tid < 64) rr[tid] = rsqrtf(ss_s[row0 + tid] * (1.f / EE) + EPSF);
  __syncthreads();
  float acc[4][4];
#pragma unroll
  for (int i = 0; i < 4; ++i)
#pragma unroll
    for (int j = 0; j < 4; ++j) acc[i][j] = 0.f;
  const int tx = tid & 15, ty = tid >> 4;
  for (int kc = 0; kc < EE; kc += 16) {
#pragma unroll
    for (int j = 0; j < 4; ++j) {
      int i = tid + j * 256;
      int k = i & 15, m = i >> 4;
      As[k][m] = s_all[(size_t)(row0 + m) * EE + kc + k] * rr[m] * nw[kc + k];
      Bs[k][m] = Wc[(size_t)(col0 + m) * EE + kc + k];
    }
    __syncthreads();
#pragma unroll
    for (int k = 0; k < 16; ++k) {
      float4 a4 = *(const float4*)&As[k][tx * 4];
      float4 b4 = *(const float4*)&Bs[k][ty * 4];
      acc[0][0] += a4.x*b4.x; acc[0][1] += a4.x*b4.y; acc[0][2] += a4.x*b4.z; acc[0][3] += a4.x*b4.w;
      acc[1][0] += a4.y*b4.x; acc[1][1] += a4.y*b4.y; acc[1][2] += a4.y*b4.z; acc[1][3] += a4.y*b4.w;
      acc[2][0] += a4.z*b4.x; acc[2][1] += a4.z*b4.y; acc[2][2] += a4.z*b4.z; acc[2][3] += a4.z*b4.w;
      acc[3][0] += a4.w*b4.x; acc[3][1] += a4.w*b4.y; acc[3][2] += a4.w*b4.z; acc[3][3] += a4.w*b4.w;
    }
    __syncthreads();
  }
  float auxp = 0.f;
#pragma unroll
  for (int i = 0; i < 4; ++i) {
    int r = row0 + tx * 4 + i;
#pragma unroll
    for (int j = 0; j < 4; ++j) {
      int col = col0 + ty * 4 + j;
      float v = acc[i][j] + cb[col];
      cur_out[(size_t)r * EE + col] = v;
      float d = v - inp_all[(size_t)r * EE + col];
      auxp += d * d;
    }
  }
#pragma unroll
  for (int off = 32; off > 0; off >>= 1) auxp += __shfl_xor(auxp, off);
  if ((tid & 63) == 0) wred[tid >> 6] = auxp;
  __syncthreads();
  if (tid == 0) atomicAdd(aux_accum, wred[0] + wred[1] + wred[2] + wred[3]);
}

__global__ __launch_bounds__(256)
void k_logits(const float* __restrict__ A, const float* __restrict__ embw,
              const int* __restrict__ idxs, float* __restrict__ rowsum,
              float* __restrict__ lidx, float* __restrict__ store) {
  __shared__ __align__(16) float As[16][68];
  __shared__ __align__(16) float Bs[16][68];
  __shared__ float rowpart[64];
  const int tid = threadIdx.x;
  const int rt = blockIdx.x & 127;
  const int ct = blockIdx.x >> 7;
  const int row0 = rt * 64, col0 = ct * 64;
  float acc[4][4];
#pragma unroll
  for (int i = 0; i < 4; ++i)
#pragma unroll
    for (int j = 0; j < 4; ++j) acc[i][j] = 0.f;
  const int tx = tid & 15, ty = tid >> 4;
  for (int kc = 0; kc < EE; kc += 16) {
#pragma unroll
    for (int j = 0; j < 4; ++j) {
      int i = tid + j * 256;
      int k = i & 15, m = i >> 4;
      As[k][m] = A[(size_t)(row0 + m) * EE + kc + k];
      Bs[k][m] = embw[(size_t)(col0 + m) * EE + kc + k];
    }
    __syncthreads();
#pragma unroll
    for (int k = 0; k < 16; ++k) {
      float4 a4 = *(const float4*)&As[k][tx * 4];
      float4 b4 = *(const float4*)&Bs[k][ty * 4];
      acc[0][0] += a4.x*b4.x; acc[0][1] += a4.x*b4.y; acc[0][2] += a4.x*b4.z; acc[0][3] += a4.x*b4.w;
      acc[1][0] += a4.y*b4.x; acc[1][1] += a4.y*b4.y; acc[1][2] += a4.y*b4.z; acc[1][3] += a4.y*b4.w;
      acc[2][0] += a4.z*b4.x; acc[2][1] += a4.z*b4.y; acc[2][2] += a4.z*b4.z; acc[2][3] += a4.z*b4.w;
      acc[3][0] += a4.w*b4.x; acc[3][1] += a4.w*b4.y; acc[3][2] += a4.w*b4.z; acc[3][3] += a4.w*b4.w;
    }
    __syncthreads();
  }
  if (tid < 64) rowpart[tid] = 0.f;
  __syncthreads();
#pragma unroll
  for (int i = 0; i < 4; ++i) {
    int r = row0 + tx * 4 + i;
    int t = r >> 5, bb = r & 31;
    int idx = idxs[bb * TT + t];
    float e0 = expf(acc[i][0]);
    float e1 = expf(acc[i][1]);
    float e2 = expf(acc[i][2]);
    float e3 = expf(acc[i][3]);
    atomicAdd(&rowpart[tx * 4 + i], e0 + e1 + e2 + e3);
    int cbase = col0 + ty * 4;
#pragma unroll
    for (int j = 0; j < 4; ++j)
      if (cbase + j == idx) lidx[r] = acc[i][j];
    if (store) {
      float4 o = make_float4(acc[i][0], acc[i][1], acc[i][2], acc[i][3]);
      *(float4*)(store + ((size_t)bb * TT + t) * VV + cbase) = o;
    }
  }
  __syncthreads();
  if (tid < 64) atomicAdd(&rowsum[row0 + tid], rowpart[tid]);
}

__global__ void k_final(const float* __restrict__ rs_cur,
                        const float* __restrict__ rs_nxt,
                        const float* __restrict__ ltok,
                        const float* __restrict__ ltgt,
                        const float* __restrict__ aux_accum,
                        float* __restrict__ out) {
  float p = 0.f;
  for (int r = threadIdx.x; r < NROWS; r += 256)
    p += (ltok[r] - logf(rs_cur[r])) + (ltgt[r] - logf(rs_nxt[r]));
#pragma unroll
  for (int off = 32; off > 0; off >>= 1) p += __shfl_xor(p, off);
  __shared__ float w[4];
  if ((threadIdx.x & 63) == 0) w[threadIdx.x >> 6] = p;
  __syncthreads();
  if (threadIdx.x == 0) {
    float tot = w[0] + w[1] + w[2] + w[3];
    out[0] = -tot / (2.f * (float)NROWS);
    out[1] = aux_accum[0] * (1.f / ((float)NROWS * EE));
  }
}

// ======================= launch =======================

extern "C" void kernel_launch(void* const* d_in, const int* in_sizes, int n_in,
                              void* d_out, int out_size, void* d_ws, size_t ws_size,
                              hipStream_t stream) {
  (void)in_sizes; (void)n_in; (void)out_size; (void)ws_size;
  const int*   tokens  = (const int*)d_in[0];
  const int*   targets = (const int*)d_in[1];
  const float* embw    = (const float*)d_in[2];
  const float* bnw     = (const float*)d_in[3];
  const float* fc1w    = (const float*)d_in[4];
  const float* fc1b    = (const float*)d_in[5];
  const float* fc2w    = (const float*)d_in[6];
  const float* fc2b    = (const float*)d_in[7];
  const float* nw      = (const float*)d_in[8];
  const float* curw    = (const float*)d_in[9];
  const float* curb    = (const float*)d_in[10];
  const float* nxtw    = (const float*)d_in[11];
  const float* nxtb    = (const float*)d_in[12];
  float* out = (float*)d_out;

  // d_out doubles as scratch for three [8192][1024] fp32 activations; the
  // final logits GEMM overwrites all of it with the real output.
  float* cur_all = out;
  float* s_all   = out + (size_t)NROWS * EE;
  float* inp_all = out + 2 * (size_t)NROWS * EE;

  float* ws      = (float*)d_ws;
  float* nxt_all = ws;                                   // 8,388,608
  float* zpart   = nxt_all + (size_t)NROWS * EE;         // 1,048,576
  float* hbuf    = zpart + 1048576;                      // 32,768
  float* cntf    = hbuf + BE;                            // 2,048 (barrier cnt)
  float* ssA     = cntf + 2048;                          // 8,192
  float* ssH     = ssA + TT * BB;                        // 8,192
  float* ssS     = ssH + TT * BB;                        // 8,192
  float* rs_cur  = ssS + TT * BB;                        // 8,192
  float* rs_nxt  = rs_cur + NROWS;                       // 8,192
  float* auxac   = rs_nxt + NROWS;                       // 1
  float* ltok    = auxac + 1;                            // 8,192
  float* ltgt    = ltok + NROWS;                         // 8,192
  float* ybuf    = ltgt + NROWS;                         // 131,072 (fallback)

  // zero: barrier counters + ssA/ssH/ssS + rs_cur/rs_nxt + auxac (contiguous)
  const int nzero = 2048 + 3 * TT * BB + 2 * NROWS + 1;
  k_zero<<<(nzero + 255) / 256, 256, 0, stream>>>(cntf, nzero);
  k_init<<<32, 256, 0, stream>>>(tokens, embw, inp_all);

  ScanParams p;
  p.tokens = tokens; p.embw = embw; p.bnw = bnw;
  p.fc1w = fc1w; p.fc1b = fc1b; p.fc2w = fc2w; p.fc2b = fc2b;
  p.nw = nw; p.nxtw = nxtw; p.nxtb = nxtb;
  p.inp_all = inp_all; p.s_all = s_all; p.nxt_all = nxt_all;
  p.zpart = zpart; p.hbuf = hbuf;
  p.ssA = ssA; p.ssH = ssH; p.ssS = ssS;
  p.cnt = (unsigned*)cntf;

  void* args[] = { &p };
  hipError_t err = hipLaunchCooperativeKernel((const void*)k_scan2,
                                              dim3(256), dim3(512),
                                              args, 0, stream);
  if (err != hipSuccess) {
    // Fallback: proven round-1 multi-kernel sequence.
    for (int t = 0; t < TT; ++t) {
      const float* inp = inp_all + (size_t)t * BE;
      float* s = s_all + (size_t)t * BE;
      k_fc1<<<512, 256, 0, stream>>>(inp, bnw, fc1w, fc1b, ybuf,
                                     hbuf, nullptr, fc2b);
      k_fc2<<<512, 256, 0, stream>>>(ybuf, fc2w, hbuf);
      k_fc1<<<512, 256, 0, stream>>>(hbuf, bnw + EE, fc1w + (size_t)MM * EE,
                                     fc1b + MM, ybuf, s, inp, fc2b + EE);
      k_fc2<<<512, 256, 0, stream>>>(ybuf, fc2w + (size_t)EE * MM, s);
      k_nxt<<<128, 256, 0, stream>>>(s, nw, nxtw, nxtb,
                                     nxt_all + (size_t)t * BE, ssS + t * BB,
                                     tokens, embw,
                                     (t + 1 < TT) ? inp_all + (size_t)(t + 1) * BE : nullptr,
                                     t + 1);
    }
  }

  k_curemb<<<2048, 256, 0, stream>>>(s_all, ssS, nw, curw, curb, inp_all,
                                     cur_all, auxac);
  k_logits<<<8192, 256, 0, stream>>>(cur_all, embw, tokens, rs_cur, ltok, nullptr);
  k_logits<<<8192, 256, 0, stream>>>(nxt_all, embw, targets, rs_nxt, ltgt, out);
  k_final<<<1, 256, 0, stream>>>(rs_cur, rs_nxt, ltok, ltgt, auxac,
                                 out + (size_t)NROWS * VV);
}